// Round 1
// baseline (1603.390 us; speedup 1.0000x reference)
//
#include <hip/hip_runtime.h>
#include <math.h>

#define NPIX 16384      // H*W
#define CCH  512        // channels
#define MS   262144     // 512*512
#define NS_ITERS 11

// ---------------------------------------------------------------- column sums
__global__ __launch_bounds__(256) void colsum_k(const float* __restrict__ Xc,
                                                const float* __restrict__ Xs,
                                                float* __restrict__ sums) {
  const float* X = blockIdx.z ? Xs : Xc;
  float* s = sums + blockIdx.z * CCH;
  int c = blockIdx.x * 256 + threadIdx.x;
  int r0 = blockIdx.y * 256;
  float acc = 0.f;
  #pragma unroll 4
  for (int r = 0; r < 256; ++r) acc += X[(r0 + r) * CCH + c];
  atomicAdd(&s[c], acc);
}

__global__ __launch_bounds__(256) void mean_k(const float* __restrict__ sums,
                                              float* __restrict__ mean) {
  int i = blockIdx.x * 256 + threadIdx.x;   // 0..1023
  mean[i] = sums[i] * (1.f / (float)NPIX);
}

// ------------------------------------------------- Gram: G = X^T X (split-K)
// grid (4,4,32): z>>4 = batch, z&15 = K-chunk (1024 rows each)
__global__ __launch_bounds__(256) void gram_k(const float* __restrict__ Xc,
                                              const float* __restrict__ Xs,
                                              float* __restrict__ G) {
  int b  = blockIdx.z >> 4;
  int kc = blockIdx.z & 15;
  const float* X = b ? Xs : Xc;
  float* Gb = G + b * MS;
  int bi = blockIdx.y, bj = blockIdx.x;

  __shared__ float As[8][128];
  __shared__ float Bs[8][128];
  int tid = threadIdx.x;
  int lk = tid >> 5, li4 = (tid & 31) * 4;   // staging: k-row, 4-float col
  int tx = tid & 15, ty = tid >> 4;          // compute: 16x16 threads
  float acc[8][8] = {};

  int k0 = kc * 1024;
  for (int kk = 0; kk < 1024; kk += 8) {
    int krow = (k0 + kk + lk) * CCH;
    float4 va = *(const float4*)&X[krow + bi * 128 + li4];
    float4 vb = *(const float4*)&X[krow + bj * 128 + li4];
    __syncthreads();
    *(float4*)&As[lk][li4] = va;
    *(float4*)&Bs[lk][li4] = vb;
    __syncthreads();
    #pragma unroll
    for (int k = 0; k < 8; ++k) {
      float a[8], bb[8];
      *(float4*)&a[0]  = *(const float4*)&As[k][ty * 8];
      *(float4*)&a[4]  = *(const float4*)&As[k][ty * 8 + 4];
      *(float4*)&bb[0] = *(const float4*)&Bs[k][tx * 8];
      *(float4*)&bb[4] = *(const float4*)&Bs[k][tx * 8 + 4];
      #pragma unroll
      for (int r = 0; r < 8; ++r)
        #pragma unroll
        for (int c = 0; c < 8; ++c) acc[r][c] += a[r] * bb[c];
    }
    __syncthreads();
  }
  #pragma unroll
  for (int r = 0; r < 8; ++r) {
    int row = bi * 128 + ty * 8 + r;
    #pragma unroll
    for (int c = 0; c < 8; ++c)
      atomicAdd(&Gb[row * CCH + bj * 128 + tx * 8 + c], acc[r][c]);
  }
}

// ------------------------------------- cov = (G - s s^T/N)/(N-1) + eps I (in place)
__global__ __launch_bounds__(256) void cov_k(float* __restrict__ G,
                                             const float* __restrict__ sums) {
  int idx = blockIdx.x * 256 + threadIdx.x;   // 0 .. 2*MS-1
  int b = idx >> 18;
  int ij = idx & (MS - 1);
  int i = ij >> 9, j = ij & 511;
  const float* s = sums + b * CCH;
  float v = (G[idx] - s[i] * s[j] * (1.f / (float)NPIX)) * (1.f / (float)(NPIX - 1));
  if (i == j) v += 1e-8f;
  G[idx] = v;
}

// ------------------------------------- row-sum norm (upper bound on lambda_max)
__global__ __launch_bounds__(256) void norm_k(const float* __restrict__ cov,
                                              float* __restrict__ snorm) {
  const float* A = cov + blockIdx.x * MS;
  float m = 0.f;
  for (int rr = 0; rr < 2; ++rr) {
    int i = threadIdx.x + rr * 256;
    float rs = 0.f;
    for (int j = 0; j < 512; ++j) rs += fabsf(A[i * CCH + j]);
    m = fmaxf(m, rs);
  }
  __shared__ float red[256];
  red[threadIdx.x] = m;
  __syncthreads();
  for (int s = 128; s > 0; s >>= 1) {
    if (threadIdx.x < s) red[threadIdx.x] = fmaxf(red[threadIdx.x], red[threadIdx.x + s]);
    __syncthreads();
  }
  if (threadIdx.x == 0) snorm[blockIdx.x] = red[0];
}

// ------------------------------------- NS init: Y0 = cov/s, Z0 = I
__global__ __launch_bounds__(256) void nsinit_k(const float* __restrict__ cov,
                                                const float* __restrict__ snorm,
                                                float* __restrict__ Y,
                                                float* __restrict__ Z) {
  int idx = blockIdx.x * 256 + threadIdx.x;   // 0 .. 2*MS-1
  int b = idx >> 18;
  int ij = idx & (MS - 1);
  float inv = 1.f / snorm[b];
  Y[idx] = cov[idx] * inv;
  Z[idx] = ((ij >> 9) == (ij & 511)) ? 1.f : 0.f;
}

__global__ void coef_k(const float* __restrict__ snorm, float* __restrict__ coef) {
  coef[0] = 0.8f * sqrtf(snorm[1] / snorm[0]);
}

// ------------------------------------- generic 512x512x512 matmul, 64x64 tiles
// D = diag*I + scale*(coef?)*A@B ; per-z pointer sets enable batching/fusion.
struct MMArgs {
  const float* A[4];
  const float* B[4];
  float* D[4];
  float scale;
  float diag;
  const float* coefPtr;
};

__global__ __launch_bounds__(256) void mm512_k(MMArgs args) {
  int z = blockIdx.z;
  const float* __restrict__ A = args.A[z];
  const float* __restrict__ B = args.B[z];
  float* __restrict__ D = args.D[z];

  __shared__ float As[16][68];   // transposed stage, padded (2-way max)
  __shared__ float Bs[16][64];
  int tid = threadIdx.x;
  int tx = tid & 15, ty = tid >> 4;
  int bi = blockIdx.y, bj = blockIdx.x;
  int ai = tid >> 2, akq = tid & 3;      // A stage: row, k-quad
  int bk = tid >> 4, bj4 = (tid & 15) * 4;

  float acc[4][4] = {};
  for (int k0 = 0; k0 < 512; k0 += 16) {
    float4 va = *(const float4*)&A[(bi * 64 + ai) * CCH + k0 + akq * 4];
    float4 vb = *(const float4*)&B[(k0 + bk) * CCH + bj * 64 + bj4];
    __syncthreads();
    As[akq * 4 + 0][ai] = va.x;
    As[akq * 4 + 1][ai] = va.y;
    As[akq * 4 + 2][ai] = va.z;
    As[akq * 4 + 3][ai] = va.w;
    *(float4*)&Bs[bk][bj4] = vb;
    __syncthreads();
    #pragma unroll
    for (int k = 0; k < 16; ++k) {
      float4 a4 = *(const float4*)&As[k][ty * 4];
      float4 b4 = *(const float4*)&Bs[k][tx * 4];
      float af[4] = {a4.x, a4.y, a4.z, a4.w};
      float bf[4] = {b4.x, b4.y, b4.z, b4.w};
      #pragma unroll
      for (int r = 0; r < 4; ++r)
        #pragma unroll
        for (int c = 0; c < 4; ++c) acc[r][c] += af[r] * bf[c];
    }
    __syncthreads();
  }

  float sc = args.scale;
  if (args.coefPtr) sc *= *args.coefPtr;
  int row0 = bi * 64 + ty * 4, col0 = bj * 64 + tx * 4;
  #pragma unroll
  for (int r = 0; r < 4; ++r) {
    #pragma unroll
    for (int c = 0; c < 4; ++c) {
      float v = sc * acc[r][c];
      if ((row0 + r) == (col0 + c)) v += args.diag;
      D[(row0 + r) * CCH + col0 + c] = v;
    }
  }
}

// ------------------------------------- apply: out = (X-mc)@Mt*1 + a*ms + (1-a)*X
__global__ __launch_bounds__(256) void apply_k(const float* __restrict__ X,
                                               const float* __restrict__ Mt,
                                               const float* __restrict__ mean,
                                               float* __restrict__ out) {
  int bc = blockIdx.x, bn = blockIdx.y;
  __shared__ float As[8][128];
  __shared__ float Bs[8][128];
  int tid = threadIdx.x;
  int ai = tid >> 1, ajq = (tid & 1) * 4;       // A stage
  int bk = tid >> 5, bc4 = (tid & 31) * 4;      // B stage
  int tx = tid & 15, ty = tid >> 4;
  float acc[8][8] = {};
  int n0 = bn * 128, c0 = bc * 128;

  for (int j0 = 0; j0 < 512; j0 += 8) {
    float4 va = *(const float4*)&X[(n0 + ai) * CCH + j0 + ajq];
    float4 vm = *(const float4*)&mean[j0 + ajq];
    va.x -= vm.x; va.y -= vm.y; va.z -= vm.z; va.w -= vm.w;
    float4 vb = *(const float4*)&Mt[(j0 + bk) * CCH + c0 + bc4];
    __syncthreads();
    As[ajq + 0][ai] = va.x;
    As[ajq + 1][ai] = va.y;
    As[ajq + 2][ai] = va.z;
    As[ajq + 3][ai] = va.w;
    *(float4*)&Bs[bk][bc4] = vb;
    __syncthreads();
    #pragma unroll
    for (int k = 0; k < 8; ++k) {
      float a[8], bb[8];
      *(float4*)&a[0]  = *(const float4*)&As[k][ty * 8];
      *(float4*)&a[4]  = *(const float4*)&As[k][ty * 8 + 4];
      *(float4*)&bb[0] = *(const float4*)&Bs[k][tx * 8];
      *(float4*)&bb[4] = *(const float4*)&Bs[k][tx * 8 + 4];
      #pragma unroll
      for (int r = 0; r < 8; ++r)
        #pragma unroll
        for (int c = 0; c < 8; ++c) acc[r][c] += a[r] * bb[c];
    }
    __syncthreads();
  }

  #pragma unroll
  for (int r = 0; r < 8; ++r) {
    int n = n0 + ty * 8 + r;
    #pragma unroll
    for (int cq = 0; cq < 8; cq += 4) {
      int c = c0 + tx * 8 + cq;
      float4 xv  = *(const float4*)&X[n * CCH + c];
      float4 msv = *(const float4*)&mean[CCH + c];
      float4 o;
      o.x = acc[r][cq + 0] + 0.8f * msv.x + 0.2f * xv.x;
      o.y = acc[r][cq + 1] + 0.8f * msv.y + 0.2f * xv.y;
      o.z = acc[r][cq + 2] + 0.8f * msv.z + 0.2f * xv.z;
      o.w = acc[r][cq + 3] + 0.8f * msv.w + 0.2f * xv.w;
      *(float4*)&out[n * CCH + c] = o;
    }
  }
}

// ---------------------------------------------------------------- launcher
extern "C" void kernel_launch(void* const* d_in, const int* in_sizes, int n_in,
                              void* d_out, int out_size, void* d_ws, size_t ws_size,
                              hipStream_t stream) {
  const float* Xc = (const float*)d_in[0];
  const float* Xs = (const float*)d_in[1];
  float* out = (float*)d_out;

  float* f = (float*)d_ws;
  float* sums  = f;                    // 1024
  float* G     = f + 1024;             // 2*MS (becomes cov in place)
  float* mean  = f + 1024 + 2 * MS;    // 1024
  float* snorm = mean + 1024;          // 2
  float* coef  = snorm + 2;            // 1
  float* Y0 = f + 527360;              // each Y/Z/T holds 2 batches (2*MS)
  float* Y1 = Y0 + 2 * MS;
  float* Z0 = Y1 + 2 * MS;
  float* Z1 = Z0 + 2 * MS;
  float* T  = Z1 + 2 * MS;
  float* Mt = T + 2 * MS;              // MS

  // zero the accumulators (sums + G are adjacent)
  hipMemsetAsync(d_ws, 0, (1024 + 2 * MS) * sizeof(float), stream);

  colsum_k<<<dim3(2, 64, 2), 256, 0, stream>>>(Xc, Xs, sums);
  mean_k<<<4, 256, 0, stream>>>(sums, mean);
  gram_k<<<dim3(4, 4, 32), 256, 0, stream>>>(Xc, Xs, G);
  cov_k<<<2048, 256, 0, stream>>>(G, sums);
  norm_k<<<2, 256, 0, stream>>>(G, snorm);
  nsinit_k<<<2048, 256, 0, stream>>>(G, snorm, Y0, Z0);

  float* Yc = Y0; float* Yn = Y1;
  float* Zc = Z0; float* Zn = Z1;
  for (int it = 0; it < NS_ITERS; ++it) {
    MMArgs t{};
    for (int b = 0; b < 2; ++b) {
      t.A[b] = Zc + b * MS; t.B[b] = Yc + b * MS; t.D[b] = T + b * MS;
    }
    t.scale = -1.f; t.diag = 3.f; t.coefPtr = nullptr;
    mm512_k<<<dim3(8, 8, 2), 256, 0, stream>>>(t);

    MMArgs yz{};
    for (int b = 0; b < 2; ++b) {
      yz.A[b]     = Yc + b * MS; yz.B[b]     = T + b * MS;  yz.D[b]     = Yn + b * MS;
      yz.A[2 + b] = T + b * MS;  yz.B[2 + b] = Zc + b * MS; yz.D[2 + b] = Zn + b * MS;
    }
    yz.scale = 0.5f; yz.diag = 0.f; yz.coefPtr = nullptr;
    mm512_k<<<dim3(8, 8, 4), 256, 0, stream>>>(yz);

    float* tmp;
    tmp = Yc; Yc = Yn; Yn = tmp;
    tmp = Zc; Zc = Zn; Zn = tmp;
  }

  coef_k<<<1, 1, 0, stream>>>(snorm, coef);

  // Mt = coef * Zc_content @ Ys_style  (both symmetric -> this is M^T directly)
  MMArgs m{};
  m.A[0] = Zc;            // content batch 0 -> cov_c^{-1/2} * sqrt(s_c)
  m.B[0] = Yc + MS;       // style batch 1   -> cov_s^{+1/2} / sqrt(s_s)
  m.D[0] = Mt;
  m.scale = 1.f; m.diag = 0.f; m.coefPtr = coef;
  mm512_k<<<dim3(8, 8, 1), 256, 0, stream>>>(m);

  apply_k<<<dim3(4, 128), 256, 0, stream>>>(Xc, Mt, mean, out);
}

// Round 2
// 614.025 us; speedup vs baseline: 2.6113x; 2.6113x over previous
//
#include <hip/hip_runtime.h>
#include <math.h>

#define NPIX 16384      // H*W
#define CCH  512        // channels
#define MS   262144     // 512*512
#define NS_ITERS 8

typedef unsigned short u16;
typedef unsigned int u32;
typedef __attribute__((ext_vector_type(8))) short bf16x8;   // 8 bf16 = 4 VGPR
typedef __attribute__((ext_vector_type(4))) float f32x4;

__device__ __forceinline__ u16 f2bf(float f) {
  u32 u = __builtin_bit_cast(u32, f);
  u += 0x7fffu + ((u >> 16) & 1u);    // round-to-nearest-even
  return (u16)(u >> 16);
}

typedef const __attribute__((address_space(1))) u32* gp_t;
typedef __attribute__((address_space(3))) u32* lp_t;
__device__ __forceinline__ void gl_lds16(const void* g, void* l) {
  // async global->LDS, 16B per lane; LDS dst = wave-uniform base + lane*16
  __builtin_amdgcn_global_load_lds((gp_t)g, (lp_t)l, 16, 0, 0);
}

// ---------------------------------------------------------------- column sums
__global__ __launch_bounds__(256) void colsum_k(const float* __restrict__ Xc,
                                                const float* __restrict__ Xs,
                                                float* __restrict__ sums) {
  const float* X = blockIdx.z ? Xs : Xc;
  float* s = sums + blockIdx.z * CCH;
  int c = blockIdx.x * 256 + threadIdx.x;
  int r0 = blockIdx.y * 256;
  float acc = 0.f;
  #pragma unroll 4
  for (int r = 0; r < 256; ++r) acc += X[(size_t)(r0 + r) * CCH + c];
  atomicAdd(&s[c], acc);
}

__global__ __launch_bounds__(256) void mean_k(const float* __restrict__ sums,
                                              float* __restrict__ mean) {
  int i = blockIdx.x * 256 + threadIdx.x;   // 0..1023
  mean[i] = sums[i] * (1.f / (float)NPIX);
}

// ---------------------- transpose + center + bf16: fct[b][c][n] = bf16(X[n][c]-m[c])
__global__ __launch_bounds__(256) void tc_k(const float* __restrict__ Xc,
                                            const float* __restrict__ Xs,
                                            const float* __restrict__ mean,
                                            u16* __restrict__ fct) {
  int b = blockIdx.z;
  const float* X = b ? Xs : Xc;
  const float* mb = mean + b * CCH;
  u16* out = fct + (size_t)b * ((size_t)CCH * NPIX);
  __shared__ float T[64][65];
  int n0 = blockIdx.x * 64, c0 = blockIdx.y * 64;
  int t = threadIdx.x;
  int cr = t & 15, nr = t >> 4;
  float4 m4 = *(const float4*)&mb[c0 + cr * 4];
  #pragma unroll
  for (int rr = 0; rr < 4; ++rr) {
    int n = nr + rr * 16;
    float4 v = *(const float4*)&X[(size_t)(n0 + n) * CCH + c0 + cr * 4];
    T[n][cr * 4 + 0] = v.x - m4.x;
    T[n][cr * 4 + 1] = v.y - m4.y;
    T[n][cr * 4 + 2] = v.z - m4.z;
    T[n][cr * 4 + 3] = v.w - m4.w;
  }
  __syncthreads();
  int cl = t >> 2, np = (t & 3) * 16;
  size_t obase = (size_t)(c0 + cl) * NPIX + n0 + np;
  #pragma unroll
  for (int i = 0; i < 16; i += 4) {
    ushort4 o;
    o.x = f2bf(T[np + i + 0][cl]);
    o.y = f2bf(T[np + i + 1][cl]);
    o.z = f2bf(T[np + i + 2][cl]);
    o.w = f2bf(T[np + i + 3][cl]);
    *(ushort4*)&out[obase + i] = o;
  }
}

// ---------------------- fcb[n][c] = bf16(Xc[n][c] - mc[c])  (apply A-operand)
__global__ __launch_bounds__(256) void fcb_k(const float* __restrict__ X,
                                             const float* __restrict__ mean,
                                             u16* __restrict__ fcb) {
  int idx = blockIdx.x * 256 + threadIdx.x;     // float4 index
  int c4 = (idx & 127) * 4;
  size_t off = (size_t)idx * 4;
  float4 v = *(const float4*)&X[off];
  float4 m = *(const float4*)&mean[c4];
  ushort4 o;
  o.x = f2bf(v.x - m.x); o.y = f2bf(v.y - m.y);
  o.z = f2bf(v.z - m.z); o.w = f2bf(v.w - m.w);
  *(ushort4*)&fcb[off] = o;
}

// ---------------------- Gram via MFMA: G[b] = fct[b] @ fct[b]^T, split-K atomic
__global__ __launch_bounds__(256) void gram_mfma(const u16* __restrict__ fct,
                                                 float* __restrict__ G) {
  int z = blockIdx.z;                // batch*8 + kchunk
  int b = z >> 3, kc = z & 7;
  const u16* Xb = fct + (size_t)b * ((size_t)CCH * NPIX);
  float* Gb = G + (size_t)b * MS;
  int bi = blockIdx.y, bj = blockIdx.x;
  __shared__ u16 As[128 * 32];
  __shared__ u16 Bs[128 * 32];
  int tid = threadIdx.x, w = tid >> 6, lane = tid & 63;
  int qm = w & 1, qn = w >> 1;
  int srow = lane >> 2, scol = (lane & 3) * 8;
  f32x4 acc[4][4];
  #pragma unroll
  for (int t = 0; t < 4; ++t)
    #pragma unroll
    for (int u = 0; u < 4; ++u) acc[t][u] = (f32x4)(0.f);

  int k0base = kc * 2048;
  for (int kk = 0; kk < 2048; kk += 32) {
    int k0 = k0base + kk;
    int r = w * 32 + srow;
    __syncthreads();
    gl_lds16(Xb + (size_t)(bi * 128 + r) * NPIX + k0 + scol,      &As[(w * 32) * 32]);
    gl_lds16(Xb + (size_t)(bi * 128 + r + 16) * NPIX + k0 + scol, &As[(w * 32 + 16) * 32]);
    gl_lds16(Xb + (size_t)(bj * 128 + r) * NPIX + k0 + scol,      &Bs[(w * 32) * 32]);
    gl_lds16(Xb + (size_t)(bj * 128 + r + 16) * NPIX + k0 + scol, &Bs[(w * 32 + 16) * 32]);
    __syncthreads();
    bf16x8 a[4], bb[4];
    #pragma unroll
    for (int t = 0; t < 4; ++t)
      a[t] = *(const bf16x8*)&As[(qm * 64 + t * 16 + (lane & 15)) * 32 + (lane >> 4) * 8];
    #pragma unroll
    for (int u = 0; u < 4; ++u)
      bb[u] = *(const bf16x8*)&Bs[(qn * 64 + u * 16 + (lane & 15)) * 32 + (lane >> 4) * 8];
    #pragma unroll
    for (int t = 0; t < 4; ++t)
      #pragma unroll
      for (int u = 0; u < 4; ++u)
        acc[t][u] = __builtin_amdgcn_mfma_f32_16x16x32_bf16(a[t], bb[u], acc[t][u], 0, 0, 0);
  }
  #pragma unroll
  for (int t = 0; t < 4; ++t) {
    int row0 = bi * 128 + qm * 64 + t * 16 + (lane >> 4) * 4;
    #pragma unroll
    for (int u = 0; u < 4; ++u) {
      int col = bj * 128 + qn * 64 + u * 16 + (lane & 15);
      #pragma unroll
      for (int r4 = 0; r4 < 4; ++r4)
        atomicAdd(&Gb[(size_t)(row0 + r4) * CCH + col], acc[t][u][r4]);
    }
  }
}

// ---------------------- cov = G/(N-1) + eps I (in place; data already centered)
__global__ __launch_bounds__(256) void cov_k(float* __restrict__ G) {
  int idx = blockIdx.x * 256 + threadIdx.x;   // 0 .. 2*MS-1
  int ij = idx & (MS - 1);
  float v = G[idx] * (1.f / (float)(NPIX - 1));
  if ((ij >> 9) == (ij & 511)) v += 1e-8f;
  G[idx] = v;
}

// ---------------------- row-sum norm
__global__ __launch_bounds__(256) void norm_k(const float* __restrict__ cov,
                                              float* __restrict__ snorm) {
  const float* A = cov + (size_t)blockIdx.x * MS;
  float m = 0.f;
  for (int rr = 0; rr < 2; ++rr) {
    int i = threadIdx.x + rr * 256;
    float rs = 0.f;
    for (int j = 0; j < 512; ++j) rs += fabsf(A[(size_t)i * CCH + j]);
    m = fmaxf(m, rs);
  }
  __shared__ float red[256];
  red[threadIdx.x] = m;
  __syncthreads();
  for (int s = 128; s > 0; s >>= 1) {
    if (threadIdx.x < s) red[threadIdx.x] = fmaxf(red[threadIdx.x], red[threadIdx.x + s]);
    __syncthreads();
  }
  if (threadIdx.x == 0) snorm[blockIdx.x] = red[0];
}

// ---------------------- NS init: An = cov/s (fp32), Yb = bf16(An), Zb = I (bf16)
__global__ __launch_bounds__(256) void nsinit_k(const float* __restrict__ cov,
                                                const float* __restrict__ snorm,
                                                float* __restrict__ An,
                                                u16* __restrict__ Yb,
                                                u16* __restrict__ Zb) {
  int idx = blockIdx.x * 256 + threadIdx.x;   // 0 .. 2*MS-1
  int b = idx >> 18;
  int ij = idx & (MS - 1);
  float inv = 1.f / snorm[b];
  float a = cov[idx] * inv;
  An[idx] = a;
  Yb[idx] = f2bf(a);
  Zb[idx] = ((ij >> 9) == (ij & 511)) ? (u16)0x3F80 : (u16)0;
}

__global__ void coef_k(const float* __restrict__ snorm, float* __restrict__ coef) {
  coef[0] = 0.8f * sqrtf(snorm[1] / snorm[0]);
}

// ---------------------- bf16 MFMA 512x512x512: D = diag*I + scale*(A @ Bst^T)
// Bst is stored row-major [n][k]; valid as A@B when B symmetric (NS matrices).
struct MM16 {
  const u16* A[4];
  const u16* B[4];
  void* D[4];
  float scale, diag;
  int outFp32;
};

__global__ __launch_bounds__(256) void mm16_k(MM16 args) {
  int z = blockIdx.z;
  const u16* __restrict__ A = args.A[z];
  const u16* __restrict__ B = args.B[z];
  int bi = blockIdx.y, bj = blockIdx.x;
  __shared__ u16 As[128 * 32];
  __shared__ u16 Bs[128 * 32];
  int tid = threadIdx.x, w = tid >> 6, lane = tid & 63;
  int qm = w & 1, qn = w >> 1;
  int srow = lane >> 2, scol = (lane & 3) * 8;
  f32x4 acc[4][4];
  #pragma unroll
  for (int t = 0; t < 4; ++t)
    #pragma unroll
    for (int u = 0; u < 4; ++u) acc[t][u] = (f32x4)(0.f);

  for (int k0 = 0; k0 < 512; k0 += 32) {
    int r = w * 32 + srow;
    __syncthreads();
    gl_lds16(A + (size_t)(bi * 128 + r) * CCH + k0 + scol,      &As[(w * 32) * 32]);
    gl_lds16(A + (size_t)(bi * 128 + r + 16) * CCH + k0 + scol, &As[(w * 32 + 16) * 32]);
    gl_lds16(B + (size_t)(bj * 128 + r) * CCH + k0 + scol,      &Bs[(w * 32) * 32]);
    gl_lds16(B + (size_t)(bj * 128 + r + 16) * CCH + k0 + scol, &Bs[(w * 32 + 16) * 32]);
    __syncthreads();
    bf16x8 a[4], bb[4];
    #pragma unroll
    for (int t = 0; t < 4; ++t)
      a[t] = *(const bf16x8*)&As[(qm * 64 + t * 16 + (lane & 15)) * 32 + (lane >> 4) * 8];
    #pragma unroll
    for (int u = 0; u < 4; ++u)
      bb[u] = *(const bf16x8*)&Bs[(qn * 64 + u * 16 + (lane & 15)) * 32 + (lane >> 4) * 8];
    #pragma unroll
    for (int t = 0; t < 4; ++t)
      #pragma unroll
      for (int u = 0; u < 4; ++u)
        acc[t][u] = __builtin_amdgcn_mfma_f32_16x16x32_bf16(a[t], bb[u], acc[t][u], 0, 0, 0);
  }
  float sc = args.scale;
  if (args.outFp32) {
    float* D = (float*)args.D[z];
    #pragma unroll
    for (int t = 0; t < 4; ++t) {
      int row0 = bi * 128 + qm * 64 + t * 16 + (lane >> 4) * 4;
      #pragma unroll
      for (int u = 0; u < 4; ++u) {
        int col = bj * 128 + qn * 64 + u * 16 + (lane & 15);
        #pragma unroll
        for (int r4 = 0; r4 < 4; ++r4) {
          float v = sc * acc[t][u][r4];
          if (row0 + r4 == col) v += args.diag;
          D[(size_t)(row0 + r4) * CCH + col] = v;
        }
      }
    }
  } else {
    u16* D = (u16*)args.D[z];
    #pragma unroll
    for (int t = 0; t < 4; ++t) {
      int row0 = bi * 128 + qm * 64 + t * 16 + (lane >> 4) * 4;
      #pragma unroll
      for (int u = 0; u < 4; ++u) {
        int col = bj * 128 + qn * 64 + u * 16 + (lane & 15);
        #pragma unroll
        for (int r4 = 0; r4 < 4; ++r4) {
          float v = sc * acc[t][u][r4];
          if (row0 + r4 == col) v += args.diag;
          D[(size_t)(row0 + r4) * CCH + col] = f2bf(v);
        }
      }
    }
  }
}

// ---------------------- fp32 vector-ALU 512^3 matmul (true A@B, no symmetry):
// D = scale*(coef?)*A@B + beta*A_elem + diag*I ; optional bf16 mirror for z==0
struct MMArgs {
  const float* A[4];
  const float* B[4];
  float* D[4];
  float scale;
  float diag;
  float beta;
  const float* coefPtr;
  u16* D16;
};

__global__ __launch_bounds__(256) void mm512_k(MMArgs args) {
  int z = blockIdx.z;
  const float* __restrict__ A = args.A[z];
  const float* __restrict__ B = args.B[z];
  float* __restrict__ D = args.D[z];

  __shared__ float As[16][68];
  __shared__ float Bs[16][64];
  int tid = threadIdx.x;
  int tx = tid & 15, ty = tid >> 4;
  int bi = blockIdx.y, bj = blockIdx.x;
  int ai = tid >> 2, akq = tid & 3;
  int bk = tid >> 4, bj4 = (tid & 15) * 4;

  float acc[4][4] = {};
  for (int k0 = 0; k0 < 512; k0 += 16) {
    float4 va = *(const float4*)&A[(size_t)(bi * 64 + ai) * CCH + k0 + akq * 4];
    float4 vb = *(const float4*)&B[(size_t)(k0 + bk) * CCH + bj * 64 + bj4];
    __syncthreads();
    As[akq * 4 + 0][ai] = va.x;
    As[akq * 4 + 1][ai] = va.y;
    As[akq * 4 + 2][ai] = va.z;
    As[akq * 4 + 3][ai] = va.w;
    *(float4*)&Bs[bk][bj4] = vb;
    __syncthreads();
    #pragma unroll
    for (int k = 0; k < 16; ++k) {
      float4 a4 = *(const float4*)&As[k][ty * 4];
      float4 b4 = *(const float4*)&Bs[k][tx * 4];
      float af[4] = {a4.x, a4.y, a4.z, a4.w};
      float bf[4] = {b4.x, b4.y, b4.z, b4.w};
      #pragma unroll
      for (int r = 0; r < 4; ++r)
        #pragma unroll
        for (int c = 0; c < 4; ++c) acc[r][c] += af[r] * bf[c];
    }
    __syncthreads();
  }

  float sc = args.scale;
  if (args.coefPtr) sc *= *args.coefPtr;
  int row0 = bi * 64 + ty * 4, col0 = bj * 64 + tx * 4;
  #pragma unroll
  for (int r = 0; r < 4; ++r) {
    #pragma unroll
    for (int c = 0; c < 4; ++c) {
      int row = row0 + r, col = col0 + c;
      float v = sc * acc[r][c];
      if (args.beta != 0.f) v += args.beta * A[(size_t)row * CCH + col];
      if (row == col) v += args.diag;
      D[(size_t)row * CCH + col] = v;
      if (args.D16 && z == 0) args.D16[(size_t)row * CCH + col] = f2bf(v);
    }
  }
}

// ---------------------- apply: out[n][c] = (fcb @ M^T)[n][c] + 0.8 ms[c] + 0.2 X[n][c]
// Mb stored row-major [c_out][k] (i.e. M), bt-form gives exactly fc @ M^T.
__global__ __launch_bounds__(256) void apply_mfma(const u16* __restrict__ fcb,
                                                  const u16* __restrict__ Mb,
                                                  const float* __restrict__ mean,
                                                  const float* __restrict__ X,
                                                  float* __restrict__ out) {
  int bi = blockIdx.y;    // n tile (0..127)
  int bj = blockIdx.x;    // c tile (0..3)
  __shared__ u16 As[128 * 32];
  __shared__ u16 Bs[128 * 32];
  int tid = threadIdx.x, w = tid >> 6, lane = tid & 63;
  int qm = w & 1, qn = w >> 1;
  int srow = lane >> 2, scol = (lane & 3) * 8;
  f32x4 acc[4][4];
  #pragma unroll
  for (int t = 0; t < 4; ++t)
    #pragma unroll
    for (int u = 0; u < 4; ++u) acc[t][u] = (f32x4)(0.f);

  for (int k0 = 0; k0 < 512; k0 += 32) {
    int r = w * 32 + srow;
    __syncthreads();
    gl_lds16(fcb + (size_t)(bi * 128 + r) * CCH + k0 + scol,      &As[(w * 32) * 32]);
    gl_lds16(fcb + (size_t)(bi * 128 + r + 16) * CCH + k0 + scol, &As[(w * 32 + 16) * 32]);
    gl_lds16(Mb + (size_t)(bj * 128 + r) * CCH + k0 + scol,       &Bs[(w * 32) * 32]);
    gl_lds16(Mb + (size_t)(bj * 128 + r + 16) * CCH + k0 + scol,  &Bs[(w * 32 + 16) * 32]);
    __syncthreads();
    bf16x8 a[4], bb[4];
    #pragma unroll
    for (int t = 0; t < 4; ++t)
      a[t] = *(const bf16x8*)&As[(qm * 64 + t * 16 + (lane & 15)) * 32 + (lane >> 4) * 8];
    #pragma unroll
    for (int u = 0; u < 4; ++u)
      bb[u] = *(const bf16x8*)&Bs[(qn * 64 + u * 16 + (lane & 15)) * 32 + (lane >> 4) * 8];
    #pragma unroll
    for (int t = 0; t < 4; ++t)
      #pragma unroll
      for (int u = 0; u < 4; ++u)
        acc[t][u] = __builtin_amdgcn_mfma_f32_16x16x32_bf16(a[t], bb[u], acc[t][u], 0, 0, 0);
  }
  #pragma unroll
  for (int t = 0; t < 4; ++t) {
    int row0 = bi * 128 + qm * 64 + t * 16 + (lane >> 4) * 4;
    #pragma unroll
    for (int u = 0; u < 4; ++u) {
      int col = bj * 128 + qn * 64 + u * 16 + (lane & 15);
      float msv = 0.8f * mean[CCH + col];
      #pragma unroll
      for (int r4 = 0; r4 < 4; ++r4) {
        size_t o = (size_t)(row0 + r4) * CCH + col;
        out[o] = acc[t][u][r4] + msv + 0.2f * X[o];
      }
    }
  }
}

// ---------------------------------------------------------------- launcher
extern "C" void kernel_launch(void* const* d_in, const int* in_sizes, int n_in,
                              void* d_out, int out_size, void* d_ws, size_t ws_size,
                              hipStream_t stream) {
  const float* Xc = (const float*)d_in[0];
  const float* Xs = (const float*)d_in[1];
  float* out = (float*)d_out;

  float* f = (float*)d_ws;
  float* sums  = f;                          // 1024 (zeroed with G)
  float* G     = f + 1024;                   // 2*MS -> cov in place
  float* mean  = G + 2 * MS;                 // 1024
  float* snorm = mean + 1024;                // 8
  float* coef  = snorm + 8;                  // 8
  float* An    = f + 1024 + 2 * MS + 1024 + 16;
  float* Zf    = An + 2 * MS;
  float* U     = Zf + 2 * MS;
  float* V     = U + 2 * MS;
  float* Zr    = V + 2 * MS;
  float* W2    = Zr + 2 * MS;                // MS
  float* Mf    = W2 + MS;                    // MS
  u16* h   = (u16*)(Mf + MS);
  u16* fct = h;                              // 2*512*16384
  u16* fcb = fct + (size_t)2 * CCH * NPIX;   // 16384*512
  u16* Y0  = fcb + (size_t)NPIX * CCH;
  u16* Y1  = Y0 + 2 * MS;
  u16* Z0  = Y1 + 2 * MS;
  u16* Z1  = Z0 + 2 * MS;
  u16* Tb  = Z1 + 2 * MS;
  u16* Mb  = Tb + 2 * MS;                    // MS

  hipMemsetAsync(d_ws, 0, (1024 + 2 * MS) * sizeof(float), stream);

  colsum_k<<<dim3(2, 64, 2), 256, 0, stream>>>(Xc, Xs, sums);
  mean_k<<<4, 256, 0, stream>>>(sums, mean);
  tc_k<<<dim3(256, 8, 2), 256, 0, stream>>>(Xc, Xs, mean, fct);
  fcb_k<<<8192, 256, 0, stream>>>(Xc, mean, fcb);
  gram_mfma<<<dim3(4, 4, 16), 256, 0, stream>>>(fct, G);
  cov_k<<<2048, 256, 0, stream>>>(G);
  norm_k<<<2, 256, 0, stream>>>(G, snorm);
  nsinit_k<<<2048, 256, 0, stream>>>(G, snorm, An, Y0, Z0);
  coef_k<<<1, 1, 0, stream>>>(snorm, coef);

  // bf16 Newton-Schulz: Y->A^1/2, Z->A^-1/2 (normalized space)
  u16 *Yc = Y0, *Yn = Y1, *Zc = Z0, *Zn = Z1;
  for (int it = 0; it < NS_ITERS; ++it) {
    MM16 t{};
    t.A[0] = Zc;      t.B[0] = Yc;      t.D[0] = Tb;
    t.A[1] = Zc + MS; t.B[1] = Yc + MS; t.D[1] = Tb + MS;
    t.scale = -1.f; t.diag = 3.f; t.outFp32 = 0;
    mm16_k<<<dim3(4, 4, 2), 256, 0, stream>>>(t);

    if (it < NS_ITERS - 1) {
      MM16 yz{};
      yz.A[0] = Yc;      yz.B[0] = Tb;      yz.D[0] = Yn;
      yz.A[1] = Yc + MS; yz.B[1] = Tb + MS; yz.D[1] = Yn + MS;
      yz.A[2] = Tb;      yz.B[2] = Zc;      yz.D[2] = Zn;
      yz.A[3] = Tb + MS; yz.B[3] = Zc + MS; yz.D[3] = Zn + MS;
      yz.scale = 0.5f; yz.diag = 0.f; yz.outFp32 = 0;
      mm16_k<<<dim3(4, 4, 4), 256, 0, stream>>>(yz);
      u16* tmp;
      tmp = Yc; Yc = Yn; Yn = tmp;
      tmp = Zc; Zc = Zn; Zn = tmp;
    } else {
      MM16 zf{};
      zf.A[0] = Tb;      zf.B[0] = Zc;      zf.D[0] = Zf;
      zf.A[1] = Tb + MS; zf.B[1] = Zc + MS; zf.D[1] = Zf + MS;
      zf.scale = 0.5f; zf.diag = 0.f; zf.outFp32 = 1;
      mm16_k<<<dim3(4, 4, 2), 256, 0, stream>>>(zf);
    }
  }

  // fp32 Newton refinement of Z (one step): Zr = 1.5 Zf - 0.5 Zf (An Zf) Zf
  MMArgs r1{};
  r1.A[0] = An; r1.A[1] = An + MS; r1.B[0] = Zf; r1.B[1] = Zf + MS;
  r1.D[0] = U;  r1.D[1] = U + MS;  r1.scale = 1.f;
  mm512_k<<<dim3(8, 8, 2), 256, 0, stream>>>(r1);
  MMArgs r2{};
  r2.A[0] = U; r2.A[1] = U + MS; r2.B[0] = Zf; r2.B[1] = Zf + MS;
  r2.D[0] = V; r2.D[1] = V + MS; r2.scale = 1.f;
  mm512_k<<<dim3(8, 8, 2), 256, 0, stream>>>(r2);
  MMArgs r3{};
  r3.A[0] = Zf; r3.A[1] = Zf + MS; r3.B[0] = V; r3.B[1] = V + MS;
  r3.D[0] = Zr; r3.D[1] = Zr + MS; r3.scale = -0.5f; r3.beta = 1.5f;
  mm512_k<<<dim3(8, 8, 2), 256, 0, stream>>>(r3);

  // M = coef * (An_s @ Zr_s) @ Zr_c   (rows of M are output channels)
  MMArgs wv{};
  wv.A[0] = An + MS; wv.B[0] = Zr + MS; wv.D[0] = W2; wv.scale = 1.f;
  mm512_k<<<dim3(8, 8, 1), 256, 0, stream>>>(wv);
  MMArgs mv{};
  mv.A[0] = W2; mv.B[0] = Zr; mv.D[0] = Mf; mv.scale = 1.f;
  mv.coefPtr = coef; mv.D16 = Mb;
  mm512_k<<<dim3(8, 8, 1), 256, 0, stream>>>(mv);

  apply_mfma<<<dim3(4, 128), 256, 0, stream>>>(fcb, Mb, mean, Xc, out);
}

// Round 3
// 421.771 us; speedup vs baseline: 3.8016x; 1.4558x over previous
//
#include <hip/hip_runtime.h>
#include <math.h>

#define NPIX 16384      // H*W
#define CCH  512        // channels
#define MS   262144     // 512*512
#define NS_ITERS 8

typedef unsigned short u16;
typedef unsigned int u32;
typedef __attribute__((ext_vector_type(8))) short bf16x8;   // 8 bf16 = 4 VGPR
typedef __attribute__((ext_vector_type(4))) float f32x4;

__device__ __forceinline__ u16 f2bf(float f) {
  u32 u = __builtin_bit_cast(u32, f);
  u += 0x7fffu + ((u >> 16) & 1u);    // round-to-nearest-even
  return (u16)(u >> 16);
}
__device__ __forceinline__ float b2f(u16 h) {
  u32 u = ((u32)h) << 16;
  return __builtin_bit_cast(float, u);
}

typedef const __attribute__((address_space(1))) u32* gp_t;
typedef __attribute__((address_space(3))) u32* lp_t;
__device__ __forceinline__ void gl_lds16(const void* g, void* l) {
  __builtin_amdgcn_global_load_lds((gp_t)g, (lp_t)l, 16, 0, 0);
}

// ================= prep: one pass over X -> colsums, fct (bf16 [c][n]), Xb (bf16 [n][c], content)
__global__ __launch_bounds__(256) void prep_k(const float* __restrict__ Xc,
                                              const float* __restrict__ Xs,
                                              float* __restrict__ sums,
                                              u16* __restrict__ fct,
                                              u16* __restrict__ fcb) {
  int b = blockIdx.z;
  const float* X = b ? Xs : Xc;
  u16* outT = fct + (size_t)b * ((size_t)CCH * NPIX);
  __shared__ float T[64][65];
  __shared__ float red2[64][4];
  int n0 = blockIdx.x * 64, c0 = blockIdx.y * 64;
  int t = threadIdx.x;
  int cr = t & 15, nr = t >> 4;
  #pragma unroll
  for (int rr = 0; rr < 4; ++rr) {
    int n = nr + rr * 16;
    float4 v = *(const float4*)&X[(size_t)(n0 + n) * CCH + c0 + cr * 4];
    T[n][cr * 4 + 0] = v.x;
    T[n][cr * 4 + 1] = v.y;
    T[n][cr * 4 + 2] = v.z;
    T[n][cr * 4 + 3] = v.w;
    if (b == 0) {
      ushort4 q;
      q.x = f2bf(v.x); q.y = f2bf(v.y); q.z = f2bf(v.z); q.w = f2bf(v.w);
      *(ushort4*)&fcb[(size_t)(n0 + n) * CCH + c0 + cr * 4] = q;
    }
  }
  __syncthreads();
  int cl = t >> 2, np = (t & 3) * 16;
  size_t obase = (size_t)(c0 + cl) * NPIX + n0 + np;
  float s = 0.f;
  #pragma unroll
  for (int i = 0; i < 16; i += 4) {
    float v0 = T[np + i + 0][cl], v1 = T[np + i + 1][cl];
    float v2 = T[np + i + 2][cl], v3 = T[np + i + 3][cl];
    s += v0 + v1 + v2 + v3;
    ushort4 o;
    o.x = f2bf(v0); o.y = f2bf(v1); o.z = f2bf(v2); o.w = f2bf(v3);
    *(ushort4*)&outT[obase + i] = o;
  }
  red2[cl][t & 3] = s;
  __syncthreads();
  if (t < 64) {
    float cs = red2[t][0] + red2[t][1] + red2[t][2] + red2[t][3];
    atomicAdd(&sums[b * CCH + c0 + t], cs);
  }
}

__global__ __launch_bounds__(256) void mean_k(const float* __restrict__ sums,
                                              float* __restrict__ mean) {
  int i = blockIdx.x * 256 + threadIdx.x;   // 0..1023
  mean[i] = sums[i] * (1.f / (float)NPIX);
}

// ================= Gram (upper-triangle 128-tiles, split-K=32, atomic fp32)
__global__ __launch_bounds__(256) void gram_mfma(const u16* __restrict__ fct,
                                                 float* __restrict__ G) {
  const int bi_t[10] = {0,0,0,0,1,1,1,2,2,3};
  const int bj_t[10] = {0,1,2,3,1,2,3,2,3,3};
  int b = blockIdx.z;
  int kc = blockIdx.y;
  int bi = bi_t[blockIdx.x], bj = bj_t[blockIdx.x];
  const u16* Xb = fct + (size_t)b * ((size_t)CCH * NPIX);
  float* Gb = G + (size_t)b * MS;
  __shared__ u16 As[128 * 32];
  __shared__ u16 Bs[128 * 32];
  int tid = threadIdx.x, w = tid >> 6, lane = tid & 63;
  int qm = w & 1, qn = w >> 1;
  int srow = lane >> 2, scol = (lane & 3) * 8;
  f32x4 acc[4][4];
  #pragma unroll
  for (int t = 0; t < 4; ++t)
    #pragma unroll
    for (int u = 0; u < 4; ++u) acc[t][u] = (f32x4)(0.f);

  int k0base = kc * 512;
  for (int kk = 0; kk < 512; kk += 32) {
    int k0 = k0base + kk;
    int r = w * 32 + srow;
    __syncthreads();
    gl_lds16(Xb + (size_t)(bi * 128 + r) * NPIX + k0 + scol,      &As[(w * 32) * 32]);
    gl_lds16(Xb + (size_t)(bi * 128 + r + 16) * NPIX + k0 + scol, &As[(w * 32 + 16) * 32]);
    gl_lds16(Xb + (size_t)(bj * 128 + r) * NPIX + k0 + scol,      &Bs[(w * 32) * 32]);
    gl_lds16(Xb + (size_t)(bj * 128 + r + 16) * NPIX + k0 + scol, &Bs[(w * 32 + 16) * 32]);
    __syncthreads();
    bf16x8 a[4], bb[4];
    #pragma unroll
    for (int t = 0; t < 4; ++t)
      a[t] = *(const bf16x8*)&As[(qm * 64 + t * 16 + (lane & 15)) * 32 + (lane >> 4) * 8];
    #pragma unroll
    for (int u = 0; u < 4; ++u)
      bb[u] = *(const bf16x8*)&Bs[(qn * 64 + u * 16 + (lane & 15)) * 32 + (lane >> 4) * 8];
    #pragma unroll
    for (int t = 0; t < 4; ++t)
      #pragma unroll
      for (int u = 0; u < 4; ++u)
        acc[t][u] = __builtin_amdgcn_mfma_f32_16x16x32_bf16(a[t], bb[u], acc[t][u], 0, 0, 0);
  }
  #pragma unroll
  for (int t = 0; t < 4; ++t) {
    int row0 = bi * 128 + qm * 64 + t * 16 + (lane >> 4) * 4;
    #pragma unroll
    for (int u = 0; u < 4; ++u) {
      int col = bj * 128 + qn * 64 + u * 16 + (lane & 15);
      #pragma unroll
      for (int r4 = 0; r4 < 4; ++r4)
        atomicAdd(&Gb[(size_t)(row0 + r4) * CCH + col], acc[t][u][r4]);
    }
  }
}

// ================= cov = (G - s s^T/N)/(N-1) + eps I, mirror lower tiles; rowsum |.|
__global__ __launch_bounds__(256) void cov_k(const float* __restrict__ G,
                                             const float* __restrict__ sums,
                                             float* __restrict__ cov,
                                             float* __restrict__ rowsum) {
  int idx = blockIdx.x * 256 + threadIdx.x;   // 0 .. 2*MS-1
  int b = idx >> 18;
  int ij = idx & (MS - 1);
  int i = ij >> 9, j = ij & 511;
  const float* s = sums + b * CCH;
  float g = ((i >> 7) <= (j >> 7)) ? G[(size_t)b * MS + (size_t)i * CCH + j]
                                   : G[(size_t)b * MS + (size_t)j * CCH + i];
  float v = (g - s[i] * s[j] * (1.f / (float)NPIX)) * (1.f / (float)(NPIX - 1));
  if (i == j) v += 1e-8f;
  cov[idx] = v;
  __shared__ float red[256];
  int t = threadIdx.x;
  red[t] = fabsf(v);
  __syncthreads();
  for (int st = 128; st > 0; st >>= 1) {
    if (t < st) red[t] += red[t + st];
    __syncthreads();
  }
  if (t == 0) atomicAdd(&rowsum[b * CCH + i], red[0]);
}

__global__ __launch_bounds__(256) void norm2_k(const float* __restrict__ rowsum,
                                               float* __restrict__ snorm) {
  int b = blockIdx.x, t = threadIdx.x;
  float m = fmaxf(rowsum[b * CCH + t], rowsum[b * CCH + t + 256]);
  __shared__ float red[256];
  red[t] = m;
  __syncthreads();
  for (int st = 128; st > 0; st >>= 1) {
    if (t < st) red[t] = fmaxf(red[t], red[t + st]);
    __syncthreads();
  }
  if (t == 0) snorm[b] = red[0];
}

// ================= NS init: An split (hi/lo bf16), Y0 = An_hi, Z0 = I
__global__ __launch_bounds__(256) void nsinit_k(const float* __restrict__ cov,
                                                const float* __restrict__ snorm,
                                                u16* __restrict__ Anh,
                                                u16* __restrict__ Anl,
                                                u16* __restrict__ Y0,
                                                u16* __restrict__ Z0) {
  int idx = blockIdx.x * 256 + threadIdx.x;   // 0 .. 2*MS-1
  int b = idx >> 18;
  int ij = idx & (MS - 1);
  float inv = 1.f / snorm[b];
  float a = cov[idx] * inv;
  u16 hi = f2bf(a);
  Anh[idx] = hi;
  Anl[idx] = f2bf(a - b2f(hi));
  Y0[idx] = hi;
  Z0[idx] = ((ij >> 9) == (ij & 511)) ? (u16)0x3F80 : (u16)0;
}

__global__ void coef_k(const float* __restrict__ snorm, float* __restrict__ coef) {
  coef[0] = 0.8f * sqrtf(snorm[1] / snorm[0]);
}

// ================= plain bf16 NS matmul, 64x64 tiles: D = diag*I + scale*(A @ B^T)
struct MM16 {
  const u16* A[4];
  const u16* B[4];
  void* D[4];
  float scale, diag;
  int outFp32;
};

__global__ __launch_bounds__(256) void mm16_k(MM16 args) {
  int z = blockIdx.z;
  const u16* __restrict__ A = args.A[z];
  const u16* __restrict__ B = args.B[z];
  int bi = blockIdx.y, bj = blockIdx.x;
  __shared__ u16 As[64 * 32];
  __shared__ u16 Bs[64 * 32];
  int tid = threadIdx.x, w = tid >> 6, lane = tid & 63;
  int qm = w & 1, qn = w >> 1;
  const u16* src = (w < 2) ? A : B;
  u16* dstbuf = (w < 2) ? As : Bs;
  int rbase = (w & 1) * 32;
  int tr0 = ((w < 2) ? bi : bj) * 64;
  int lrow = lane >> 2, lcol = (lane & 3) * 8;
  f32x4 acc[2][2];
  #pragma unroll
  for (int t = 0; t < 2; ++t)
    #pragma unroll
    for (int u = 0; u < 2; ++u) acc[t][u] = (f32x4)(0.f);

  for (int k0 = 0; k0 < 512; k0 += 32) {
    __syncthreads();
    gl_lds16(src + (size_t)(tr0 + rbase + lrow) * CCH + k0 + lcol,      &dstbuf[(rbase) * 32]);
    gl_lds16(src + (size_t)(tr0 + rbase + 16 + lrow) * CCH + k0 + lcol, &dstbuf[(rbase + 16) * 32]);
    __syncthreads();
    bf16x8 a[2], bb[2];
    #pragma unroll
    for (int t = 0; t < 2; ++t)
      a[t] = *(const bf16x8*)&As[(qm * 32 + t * 16 + (lane & 15)) * 32 + (lane >> 4) * 8];
    #pragma unroll
    for (int u = 0; u < 2; ++u)
      bb[u] = *(const bf16x8*)&Bs[(qn * 32 + u * 16 + (lane & 15)) * 32 + (lane >> 4) * 8];
    #pragma unroll
    for (int t = 0; t < 2; ++t)
      #pragma unroll
      for (int u = 0; u < 2; ++u)
        acc[t][u] = __builtin_amdgcn_mfma_f32_16x16x32_bf16(a[t], bb[u], acc[t][u], 0, 0, 0);
  }
  float sc = args.scale;
  #pragma unroll
  for (int t = 0; t < 2; ++t) {
    int row0 = bi * 64 + qm * 32 + t * 16 + (lane >> 4) * 4;
    #pragma unroll
    for (int u = 0; u < 2; ++u) {
      int col = bj * 64 + qn * 32 + u * 16 + (lane & 15);
      #pragma unroll
      for (int r4 = 0; r4 < 4; ++r4) {
        float v = sc * acc[t][u][r4];
        if (row0 + r4 == col) v += args.diag;
        size_t o = (size_t)(row0 + r4) * CCH + col;
        if (args.outFp32) ((float*)args.D[z])[o] = v;
        else ((u16*)args.D[z])[o] = f2bf(v);
      }
    }
  }
}

// ================= symmetrize + split fp32 -> hi/lo bf16
__global__ __launch_bounds__(256) void symsplit_k(const float* __restrict__ src,
                                                  u16* __restrict__ hi,
                                                  u16* __restrict__ lo) {
  int b = blockIdx.y;
  int ij = blockIdx.x * 256 + threadIdx.x;   // 0..MS-1
  int i = ij >> 9, j = ij & 511;
  size_t base = (size_t)b * MS;
  float v = 0.5f * (src[base + ij] + src[base + (size_t)j * CCH + i]);
  u16 h = f2bf(v);
  hi[base + ij] = h;
  lo[base + ij] = f2bf(v - b2f(h));
}

// ================= split-bf16 matmul (~fp32 quality), 64x64 tiles
// D = scale*(coef?)*(A @ B^T) + beta*(Eh+El); outputs: split / fp32 / bf16 per z
struct MMS {
  const u16 *Ah[4], *Al[4], *Bh[4], *Bl[4];
  const u16 *Eh[4], *El[4];
  u16 *Dh[4], *Dl[4];
  float *D32[4];
  u16 *Db[4];
  float scale, beta;
  const float* coefPtr;
};

__global__ __launch_bounds__(256) void mmsplit_k(MMS args) {
  int z = blockIdx.z;
  int bi = blockIdx.y, bj = blockIdx.x;
  __shared__ u16 Ash[64 * 32], Asl[64 * 32], Bsh[64 * 32], Bsl[64 * 32];
  int tid = threadIdx.x, w = tid >> 6, lane = tid & 63;
  int qm = w & 1, qn = w >> 1;
  const u16* src = (w == 0) ? args.Ah[z] : (w == 1) ? args.Al[z]
                 : (w == 2) ? args.Bh[z] : args.Bl[z];
  u16* dstbuf = (w == 0) ? Ash : (w == 1) ? Asl : (w == 2) ? Bsh : Bsl;
  int tr0 = ((w < 2) ? bi : bj) * 64;
  int lrow = lane >> 2, lcol = (lane & 3) * 8;
  f32x4 acc[2][2];
  #pragma unroll
  for (int t = 0; t < 2; ++t)
    #pragma unroll
    for (int u = 0; u < 2; ++u) acc[t][u] = (f32x4)(0.f);

  for (int k0 = 0; k0 < 512; k0 += 32) {
    __syncthreads();
    #pragma unroll
    for (int c = 0; c < 4; ++c)
      gl_lds16(src + (size_t)(tr0 + c * 16 + lrow) * CCH + k0 + lcol, &dstbuf[(c * 16) * 32]);
    __syncthreads();
    bf16x8 ah[2], al[2], bh[2], bl[2];
    #pragma unroll
    for (int t = 0; t < 2; ++t) {
      int off = (qm * 32 + t * 16 + (lane & 15)) * 32 + (lane >> 4) * 8;
      ah[t] = *(const bf16x8*)&Ash[off];
      al[t] = *(const bf16x8*)&Asl[off];
    }
    #pragma unroll
    for (int u = 0; u < 2; ++u) {
      int off = (qn * 32 + u * 16 + (lane & 15)) * 32 + (lane >> 4) * 8;
      bh[u] = *(const bf16x8*)&Bsh[off];
      bl[u] = *(const bf16x8*)&Bsl[off];
    }
    #pragma unroll
    for (int t = 0; t < 2; ++t)
      #pragma unroll
      for (int u = 0; u < 2; ++u) {
        acc[t][u] = __builtin_amdgcn_mfma_f32_16x16x32_bf16(ah[t], bh[u], acc[t][u], 0, 0, 0);
        acc[t][u] = __builtin_amdgcn_mfma_f32_16x16x32_bf16(ah[t], bl[u], acc[t][u], 0, 0, 0);
        acc[t][u] = __builtin_amdgcn_mfma_f32_16x16x32_bf16(al[t], bh[u], acc[t][u], 0, 0, 0);
      }
  }
  float sc = args.scale;
  if (args.coefPtr) sc *= *args.coefPtr;
  #pragma unroll
  for (int t = 0; t < 2; ++t) {
    int row0 = bi * 64 + qm * 32 + t * 16 + (lane >> 4) * 4;
    #pragma unroll
    for (int u = 0; u < 2; ++u) {
      int col = bj * 64 + qn * 32 + u * 16 + (lane & 15);
      #pragma unroll
      for (int r4 = 0; r4 < 4; ++r4) {
        size_t o = (size_t)(row0 + r4) * CCH + col;
        float v = sc * acc[t][u][r4];
        if (args.beta != 0.f) v += args.beta * (b2f(args.Eh[z][o]) + b2f(args.El[z][o]));
        if (args.D32[z]) args.D32[z][o] = v;
        if (args.Dh[z]) {
          u16 h = f2bf(v);
          args.Dh[z][o] = h;
          args.Dl[z][o] = f2bf(v - b2f(h));
        }
        if (args.Db[z]) args.Db[z][o] = f2bf(v);
      }
    }
  }
}

// ================= mconst[c] = 0.8*ms[c] - (M @ mc)[c]
__global__ __launch_bounds__(256) void mconst_k(const u16* __restrict__ Mb,
                                                const float* __restrict__ mean,
                                                float* __restrict__ mconst) {
  int c = blockIdx.x * 256 + threadIdx.x;   // 0..511
  float s = 0.f;
  for (int j = 0; j < CCH; ++j) s += b2f(Mb[(size_t)c * CCH + j]) * mean[j];
  mconst[c] = 0.8f * mean[CCH + c] - s;
}

// ================= apply: out = Xb @ M^T + mconst + 0.2 X
__global__ __launch_bounds__(256) void apply_mfma(const u16* __restrict__ fcb,
                                                  const u16* __restrict__ Mb,
                                                  const float* __restrict__ mconst,
                                                  const float* __restrict__ X,
                                                  float* __restrict__ out) {
  int bi = blockIdx.y;    // n tile (0..127)
  int bj = blockIdx.x;    // c tile (0..3)
  __shared__ u16 As[128 * 32];
  __shared__ u16 Bs[128 * 32];
  int tid = threadIdx.x, w = tid >> 6, lane = tid & 63;
  int qm = w & 1, qn = w >> 1;
  int srow = lane >> 2, scol = (lane & 3) * 8;
  f32x4 acc[4][4];
  #pragma unroll
  for (int t = 0; t < 4; ++t)
    #pragma unroll
    for (int u = 0; u < 4; ++u) acc[t][u] = (f32x4)(0.f);

  for (int k0 = 0; k0 < 512; k0 += 32) {
    int r = w * 32 + srow;
    __syncthreads();
    gl_lds16(fcb + (size_t)(bi * 128 + r) * CCH + k0 + scol,      &As[(w * 32) * 32]);
    gl_lds16(fcb + (size_t)(bi * 128 + r + 16) * CCH + k0 + scol, &As[(w * 32 + 16) * 32]);
    gl_lds16(Mb + (size_t)(bj * 128 + r) * CCH + k0 + scol,       &Bs[(w * 32) * 32]);
    gl_lds16(Mb + (size_t)(bj * 128 + r + 16) * CCH + k0 + scol,  &Bs[(w * 32 + 16) * 32]);
    __syncthreads();
    bf16x8 a[4], bb[4];
    #pragma unroll
    for (int t = 0; t < 4; ++t)
      a[t] = *(const bf16x8*)&As[(qm * 64 + t * 16 + (lane & 15)) * 32 + (lane >> 4) * 8];
    #pragma unroll
    for (int u = 0; u < 4; ++u)
      bb[u] = *(const bf16x8*)&Bs[(qn * 64 + u * 16 + (lane & 15)) * 32 + (lane >> 4) * 8];
    #pragma unroll
    for (int t = 0; t < 4; ++t)
      #pragma unroll
      for (int u = 0; u < 4; ++u)
        acc[t][u] = __builtin_amdgcn_mfma_f32_16x16x32_bf16(a[t], bb[u], acc[t][u], 0, 0, 0);
  }
  #pragma unroll
  for (int t = 0; t < 4; ++t) {
    int row0 = bi * 128 + qm * 64 + t * 16 + (lane >> 4) * 4;
    #pragma unroll
    for (int u = 0; u < 4; ++u) {
      int col = bj * 128 + qn * 64 + u * 16 + (lane & 15);
      float cst = mconst[col];
      #pragma unroll
      for (int r4 = 0; r4 < 4; ++r4) {
        size_t o = (size_t)(row0 + r4) * CCH + col;
        out[o] = acc[t][u][r4] + cst + 0.2f * X[o];
      }
    }
  }
}

// ================================================================ launcher
extern "C" void kernel_launch(void* const* d_in, const int* in_sizes, int n_in,
                              void* d_out, int out_size, void* d_ws, size_t ws_size,
                              hipStream_t stream) {
  const float* Xc = (const float*)d_in[0];
  const float* Xs = (const float*)d_in[1];
  float* out = (float*)d_out;

  float* f = (float*)d_ws;
  float* sums   = f;                     // 1024
  float* rowsum = f + 1024;              // 1024
  float* G      = f + 2048;              // 2*MS
  float* cov    = G + 2 * MS;            // 2*MS
  float* mean   = cov + 2 * MS;          // 1024
  float* snorm  = mean + 1024;           // 8
  float* coef   = snorm + 8;             // 8
  float* mconst = coef + 8;              // 512
  float* Zf     = mconst + 512;          // 2*MS (also reused for Zr)

  u16* h   = (u16*)(Zf + 2 * MS);
  u16* fct = h;                          // 2*512*16384 u16 (dead after gram)
  u16* fcb = h + (size_t)2 * CCH * NPIX; // 16384*512 u16
  // NS / refinement buffers alias the fct region (gram completes first):
  const size_t B2 = 2 * MS;              // u16 elements per (2-batch) buffer
  u16* Anh  = fct + 0 * B2;
  u16* Anl  = fct + 1 * B2;
  u16* Y0   = fct + 2 * B2;
  u16* Y1   = fct + 3 * B2;
  u16* Z0   = fct + 4 * B2;
  u16* Z1   = fct + 5 * B2;
  u16* Tb   = fct + 6 * B2;
  u16* Zfsh = fct + 7 * B2;
  u16* Zfsl = fct + 8 * B2;
  u16* Ph   = fct + 9 * B2;
  u16* Pl   = fct + 10 * B2;
  u16* Qh   = fct + 11 * B2;
  u16* Ql   = fct + 12 * B2;
  u16* Zrsh = fct + 13 * B2;
  u16* Zrsl = fct + 14 * B2;
  u16* W2h  = fct + 15 * B2;             // MS each from here
  u16* W2l  = W2h + MS;
  u16* Mb   = W2l + MS;

  // zero sums + rowsum + G (contiguous)
  hipMemsetAsync(d_ws, 0, (2048 + 2 * MS) * sizeof(float), stream);

  prep_k<<<dim3(256, 8, 2), 256, 0, stream>>>(Xc, Xs, sums, fct, fcb);
  mean_k<<<4, 256, 0, stream>>>(sums, mean);
  gram_mfma<<<dim3(10, 32, 2), 256, 0, stream>>>(fct, G);
  cov_k<<<2048, 256, 0, stream>>>(G, sums, cov, rowsum);
  norm2_k<<<2, 256, 0, stream>>>(rowsum, snorm);
  nsinit_k<<<2048, 256, 0, stream>>>(cov, snorm, Anh, Anl, Y0, Z0);
  coef_k<<<1, 1, 0, stream>>>(snorm, coef);

  // bf16 Newton-Schulz (64-tile): Y->A^1/2, Z->A^-1/2 (normalized space)
  u16 *Yc = Y0, *Yn = Y1, *Zc = Z0, *Zn = Z1;
  for (int it = 0; it < NS_ITERS; ++it) {
    MM16 t{};
    t.A[0] = Zc;      t.B[0] = Yc;      t.D[0] = Tb;
    t.A[1] = Zc + MS; t.B[1] = Yc + MS; t.D[1] = Tb + MS;
    t.scale = -1.f; t.diag = 3.f; t.outFp32 = 0;
    mm16_k<<<dim3(8, 8, 2), 256, 0, stream>>>(t);

    if (it < NS_ITERS - 1) {
      MM16 yz{};
      yz.A[0] = Yc;      yz.B[0] = Tb;      yz.D[0] = Yn;
      yz.A[1] = Yc + MS; yz.B[1] = Tb + MS; yz.D[1] = Yn + MS;
      yz.A[2] = Tb;      yz.B[2] = Zc;      yz.D[2] = Zn;
      yz.A[3] = Tb + MS; yz.B[3] = Zc + MS; yz.D[3] = Zn + MS;
      yz.scale = 0.5f; yz.diag = 0.f; yz.outFp32 = 0;
      mm16_k<<<dim3(8, 8, 4), 256, 0, stream>>>(yz);
      u16* tmp;
      tmp = Yc; Yc = Yn; Yn = tmp;
      tmp = Zc; Zc = Zn; Zn = tmp;
    } else {
      MM16 zf{};
      zf.A[0] = Tb;      zf.B[0] = Zc;      zf.D[0] = Zf;
      zf.A[1] = Tb + MS; zf.B[1] = Zc + MS; zf.D[1] = Zf + MS;
      zf.scale = 0.5f; zf.diag = 0.f; zf.outFp32 = 1;
      mm16_k<<<dim3(8, 8, 2), 256, 0, stream>>>(zf);
    }
  }

  // symmetrize+split Zf
  symsplit_k<<<dim3(1024, 2), 256, 0, stream>>>(Zf, Zfsh, Zfsl);

  // P_b = Zfs_b @ An_b ; Q_b = Zfs_b @ Zfs_b   (one z=4 launch, split outputs)
  MMS pq{};
  for (int b = 0; b < 2; ++b) {
    pq.Ah[b] = Zfsh + b * MS; pq.Al[b] = Zfsl + b * MS;
    pq.Bh[b] = Anh + b * MS;  pq.Bl[b] = Anl + b * MS;
    pq.Dh[b] = Ph + b * MS;   pq.Dl[b] = Pl + b * MS;
    pq.Ah[2 + b] = Zfsh + b * MS; pq.Al[2 + b] = Zfsl + b * MS;
    pq.Bh[2 + b] = Zfsh + b * MS; pq.Bl[2 + b] = Zfsl + b * MS;
    pq.Dh[2 + b] = Qh + b * MS;   pq.Dl[2 + b] = Ql + b * MS;
  }
  pq.scale = 1.f;
  mmsplit_k<<<dim3(8, 8, 4), 256, 0, stream>>>(pq);

  // Zr_b = 1.5 Zfs_b - 0.5 P_b @ Q_b  (fp32 out, reuse Zf buffer)
  MMS zr{};
  for (int b = 0; b < 2; ++b) {
    zr.Ah[b] = Ph + b * MS;   zr.Al[b] = Pl + b * MS;
    zr.Bh[b] = Qh + b * MS;   zr.Bl[b] = Ql + b * MS;
    zr.Eh[b] = Zfsh + b * MS; zr.El[b] = Zfsl + b * MS;
    zr.D32[b] = Zf + b * MS;
  }
  zr.scale = -0.5f; zr.beta = 1.5f;
  mmsplit_k<<<dim3(8, 8, 2), 256, 0, stream>>>(zr);

  // symmetrize+split Zr
  symsplit_k<<<dim3(1024, 2), 256, 0, stream>>>(Zf, Zrsh, Zrsl);

  // W2 = An_s @ Zr_s (split out)
  MMS wv{};
  wv.Ah[0] = Anh + MS; wv.Al[0] = Anl + MS;
  wv.Bh[0] = Zrsh + MS; wv.Bl[0] = Zrsl + MS;
  wv.Dh[0] = W2h; wv.Dl[0] = W2l;
  wv.scale = 1.f;
  mmsplit_k<<<dim3(8, 8, 1), 256, 0, stream>>>(wv);

  // M = coef * W2 @ Zr_c (bf16 out)
  MMS mv{};
  mv.Ah[0] = W2h; mv.Al[0] = W2l;
  mv.Bh[0] = Zrsh; mv.Bl[0] = Zrsl;
  mv.Db[0] = Mb;
  mv.scale = 1.f; mv.coefPtr = coef;
  mmsplit_k<<<dim3(8, 8, 1), 256, 0, stream>>>(mv);

  mconst_k<<<2, 256, 0, stream>>>(Mb, mean, mconst);
  apply_mfma<<<dim3(4, 128), 256, 0, stream>>>(fcb, Mb, mconst, Xc, out);
}

// Round 4
// 335.603 us; speedup vs baseline: 4.7776x; 1.2568x over previous
//
#include <hip/hip_runtime.h>
#include <math.h>

#define NPIX 16384      // H*W
#define CCH  512        // channels
#define MS   262144     // 512*512

typedef unsigned short u16;
typedef unsigned int u32;
typedef __attribute__((ext_vector_type(8))) short bf16x8;   // 8 bf16 = 4 VGPR
typedef __attribute__((ext_vector_type(4))) float f32x4;

__device__ __forceinline__ u16 f2bf(float f) {
  u32 u = __builtin_bit_cast(u32, f);
  u += 0x7fffu + ((u >> 16) & 1u);    // round-to-nearest-even
  return (u16)(u >> 16);
}
__device__ __forceinline__ float b2f(u16 h) {
  u32 u = ((u32)h) << 16;
  return __builtin_bit_cast(float, u);
}

typedef const __attribute__((address_space(1))) u32* gp_t;
typedef __attribute__((address_space(3))) u32* lp_t;
__device__ __forceinline__ void gl_lds16(const void* g, void* l) {
  __builtin_amdgcn_global_load_lds((gp_t)g, (lp_t)l, 16, 0, 0);
}

// ---- Kt=128 staged tile, XOR-swizzled: LDS row = 128 bf16 (16 chunks of 16B).
// Logical chunk c of row r lives at phys chunk c ^ (r & 15). Swizzle is applied
// on the per-lane GLOBAL address (LDS dst of global_load_lds is fixed lane*16).
__device__ __forceinline__ void stage4(const u16* tile, size_t stride, int rl,
                                       int k0, u16* lds, int lane) {
  int lr = lane >> 4;                               // 4 rows per instruction
  int cg = (lane & 15) ^ ((rl + lr) & 15);          // swizzled global chunk
  gl_lds16(tile + (size_t)(rl + lr) * stride + k0 + cg * 8,
           lds + (size_t)rl * 128);
}
__device__ __forceinline__ bf16x8 fragld(const u16* lds, int row, int cl) {
  return *(const bf16x8*)&lds[(size_t)row * 128 + (size_t)(((cl ^ (row & 15))) << 3)];
}

// ================= prep: one pass over X -> colsums, fct (bf16 [c][n]), fcb (bf16 [n][c])
__global__ __launch_bounds__(256) void prep_k(const float* __restrict__ Xc,
                                              const float* __restrict__ Xs,
                                              float* __restrict__ sums,
                                              u16* __restrict__ fct,
                                              u16* __restrict__ fcb) {
  int b = blockIdx.z;
  const float* X = b ? Xs : Xc;
  u16* outT = fct + (size_t)b * ((size_t)CCH * NPIX);
  __shared__ float T[64][65];
  __shared__ float red2[64][4];
  int n0 = blockIdx.x * 64, c0 = blockIdx.y * 64;
  int t = threadIdx.x;
  int cr = t & 15, nr = t >> 4;
  #pragma unroll
  for (int rr = 0; rr < 4; ++rr) {
    int n = nr + rr * 16;
    float4 v = *(const float4*)&X[(size_t)(n0 + n) * CCH + c0 + cr * 4];
    T[n][cr * 4 + 0] = v.x;
    T[n][cr * 4 + 1] = v.y;
    T[n][cr * 4 + 2] = v.z;
    T[n][cr * 4 + 3] = v.w;
    if (b == 0) {
      ushort4 q;
      q.x = f2bf(v.x); q.y = f2bf(v.y); q.z = f2bf(v.z); q.w = f2bf(v.w);
      *(ushort4*)&fcb[(size_t)(n0 + n) * CCH + c0 + cr * 4] = q;
    }
  }
  __syncthreads();
  int cl = t >> 2, np = (t & 3) * 16;
  size_t obase = (size_t)(c0 + cl) * NPIX + n0 + np;
  float s = 0.f;
  #pragma unroll
  for (int i = 0; i < 16; i += 4) {
    float v0 = T[np + i + 0][cl], v1 = T[np + i + 1][cl];
    float v2 = T[np + i + 2][cl], v3 = T[np + i + 3][cl];
    s += v0 + v1 + v2 + v3;
    ushort4 o;
    o.x = f2bf(v0); o.y = f2bf(v1); o.z = f2bf(v2); o.w = f2bf(v3);
    *(ushort4*)&outT[obase + i] = o;
  }
  red2[cl][t & 3] = s;
  __syncthreads();
  if (t < 64) {
    float cs = red2[t][0] + red2[t][1] + red2[t][2] + red2[t][3];
    atomicAdd(&sums[b * CCH + c0 + t], cs);
  }
}

__global__ __launch_bounds__(256) void mean_k(const float* __restrict__ sums,
                                              float* __restrict__ mean) {
  int i = blockIdx.x * 256 + threadIdx.x;   // 0..1023
  mean[i] = sums[i] * (1.f / (float)NPIX);
}

// ================= Gram (upper-tri 128-tiles, split-K=32 of 512, Kt=128 stages)
__global__ __launch_bounds__(256) void gram_mfma(const u16* __restrict__ fct,
                                                 float* __restrict__ G) {
  const int bi_t[10] = {0,0,0,0,1,1,1,2,2,3};
  const int bj_t[10] = {0,1,2,3,1,2,3,2,3,3};
  int b = blockIdx.z;
  int kc = blockIdx.y;
  int bi = bi_t[blockIdx.x], bj = bj_t[blockIdx.x];
  const u16* Xb = fct + (size_t)b * ((size_t)CCH * NPIX);
  float* Gb = G + (size_t)b * MS;
  __shared__ u16 As[128 * 128];
  __shared__ u16 Bs[128 * 128];
  int tid = threadIdx.x, w = tid >> 6, lane = tid & 63;
  int qm = w & 1, qn = w >> 1;
  const u16* At = Xb + (size_t)(bi * 128) * NPIX;
  const u16* Bt = Xb + (size_t)(bj * 128) * NPIX;
  const u16* ssrc = (w < 2) ? At : Bt;
  u16* sdst = (w < 2) ? As : Bs;
  int rbase = (w & 1) * 64;
  f32x4 acc[4][4];
  #pragma unroll
  for (int t = 0; t < 4; ++t)
    #pragma unroll
    for (int u = 0; u < 4; ++u) acc[t][u] = (f32x4)(0.f);

  for (int st = 0; st < 4; ++st) {
    int k0 = kc * 512 + st * 128;
    __syncthreads();
    #pragma unroll
    for (int i = 0; i < 16; ++i) stage4(ssrc, NPIX, rbase + i * 4, k0, sdst, lane);
    __syncthreads();
    #pragma unroll
    for (int s = 0; s < 4; ++s) {
      int cl = s * 4 + (lane >> 4);
      bf16x8 a[4], bb[4];
      #pragma unroll
      for (int t = 0; t < 4; ++t) a[t] = fragld(As, qm * 64 + t * 16 + (lane & 15), cl);
      #pragma unroll
      for (int u = 0; u < 4; ++u) bb[u] = fragld(Bs, qn * 64 + u * 16 + (lane & 15), cl);
      #pragma unroll
      for (int t = 0; t < 4; ++t)
        #pragma unroll
        for (int u = 0; u < 4; ++u)
          acc[t][u] = __builtin_amdgcn_mfma_f32_16x16x32_bf16(a[t], bb[u], acc[t][u], 0, 0, 0);
    }
  }
  #pragma unroll
  for (int t = 0; t < 4; ++t) {
    int row0 = bi * 128 + qm * 64 + t * 16 + (lane >> 4) * 4;
    #pragma unroll
    for (int u = 0; u < 4; ++u) {
      int col = bj * 128 + qn * 64 + u * 16 + (lane & 15);
      #pragma unroll
      for (int r4 = 0; r4 < 4; ++r4)
        atomicAdd(&Gb[(size_t)(row0 + r4) * CCH + col], acc[t][u][r4]);
    }
  }
}

// ================= cov = (G - s s^T/N)/(N-1) + eps I, mirror lower tiles; rowsum |.|
__global__ __launch_bounds__(256) void cov_k(const float* __restrict__ G,
                                             const float* __restrict__ sums,
                                             float* __restrict__ cov,
                                             float* __restrict__ rowsum) {
  int idx = blockIdx.x * 256 + threadIdx.x;   // 0 .. 2*MS-1
  int b = idx >> 18;
  int ij = idx & (MS - 1);
  int i = ij >> 9, j = ij & 511;
  const float* s = sums + b * CCH;
  float g = ((i >> 7) <= (j >> 7)) ? G[(size_t)b * MS + (size_t)i * CCH + j]
                                   : G[(size_t)b * MS + (size_t)j * CCH + i];
  float v = (g - s[i] * s[j] * (1.f / (float)NPIX)) * (1.f / (float)(NPIX - 1));
  if (i == j) v += 1e-8f;
  cov[idx] = v;
  __shared__ float red[256];
  int t = threadIdx.x;
  red[t] = fabsf(v);
  __syncthreads();
  for (int st = 128; st > 0; st >>= 1) {
    if (t < st) red[t] += red[t + st];
    __syncthreads();
  }
  if (t == 0) atomicAdd(&rowsum[b * CCH + i], red[0]);
}

__global__ __launch_bounds__(256) void norm2_k(const float* __restrict__ rowsum,
                                               float* __restrict__ snorm) {
  int b = blockIdx.x, t = threadIdx.x;
  float m = fmaxf(rowsum[b * CCH + t], rowsum[b * CCH + t + 256]);
  __shared__ float red[256];
  red[t] = m;
  __syncthreads();
  for (int st = 128; st > 0; st >>= 1) {
    if (t < st) red[t] = fmaxf(red[t], red[t + st]);
    __syncthreads();
  }
  if (t == 0) snorm[b] = red[0];
}

// ================= NS init: An split; Yb = Â; Zb = Z1 = (c/2)(3I - Â), c=sqrt(2)
// (fuses NS iteration 1: Z1 = c*T0/2 elementwise since Z0=I; Y1 = Â@Z1 is one mm.)
__global__ __launch_bounds__(256) void nsinit_k(const float* __restrict__ cov,
                                                const float* __restrict__ snorm,
                                                u16* __restrict__ Anh,
                                                u16* __restrict__ Anl,
                                                u16* __restrict__ Yb,
                                                u16* __restrict__ Zb) {
  int idx = blockIdx.x * 256 + threadIdx.x;   // 0 .. 2*MS-1
  int b = idx >> 18;
  int ij = idx & (MS - 1);
  int diag = (ij >> 9) == (ij & 511);
  float inv = 1.f / snorm[b];
  float a = cov[idx] * inv;
  u16 hi = f2bf(a);
  Anh[idx] = hi;
  Anl[idx] = f2bf(a - b2f(hi));
  Yb[idx] = hi;
  float t0 = (diag ? 3.f - a : -a) * 0.70710678f;   // boosted first step, c^2=2
  Zb[idx] = f2bf(t0);
}

__global__ void coef_k(const float* __restrict__ snorm, float* __restrict__ coef) {
  coef[0] = 0.8f * sqrtf(snorm[1] / snorm[0]);
}

// ================= plain bf16 NS matmul, 64x64 tiles, Kt=128: D = diag*I + scale*(A @ B^T)
struct MM16 {
  const u16* A[4];
  const u16* B[4];
  void* D[4];
  float scale, diag;
  int outFp32;
};

__global__ __launch_bounds__(256) void mm16_k(MM16 args) {
  int z = blockIdx.z;
  const u16* __restrict__ A = args.A[z];
  const u16* __restrict__ B = args.B[z];
  int bi = blockIdx.y, bj = blockIdx.x;
  __shared__ u16 As[64 * 128];
  __shared__ u16 Bs[64 * 128];
  int tid = threadIdx.x, w = tid >> 6, lane = tid & 63;
  int qm = w & 1, qn = w >> 1;
  const u16* ssrc = ((w < 2) ? A + (size_t)(bi * 64) * CCH : B + (size_t)(bj * 64) * CCH);
  u16* sdst = (w < 2) ? As : Bs;
  int rbase = (w & 1) * 32;
  f32x4 acc[2][2];
  #pragma unroll
  for (int t = 0; t < 2; ++t)
    #pragma unroll
    for (int u = 0; u < 2; ++u) acc[t][u] = (f32x4)(0.f);

  for (int st = 0; st < 4; ++st) {
    int k0 = st * 128;
    __syncthreads();
    #pragma unroll
    for (int i = 0; i < 8; ++i) stage4(ssrc, CCH, rbase + i * 4, k0, sdst, lane);
    __syncthreads();
    #pragma unroll
    for (int s = 0; s < 4; ++s) {
      int cl = s * 4 + (lane >> 4);
      bf16x8 a[2], bb[2];
      #pragma unroll
      for (int t = 0; t < 2; ++t) a[t] = fragld(As, qm * 32 + t * 16 + (lane & 15), cl);
      #pragma unroll
      for (int u = 0; u < 2; ++u) bb[u] = fragld(Bs, qn * 32 + u * 16 + (lane & 15), cl);
      #pragma unroll
      for (int t = 0; t < 2; ++t)
        #pragma unroll
        for (int u = 0; u < 2; ++u)
          acc[t][u] = __builtin_amdgcn_mfma_f32_16x16x32_bf16(a[t], bb[u], acc[t][u], 0, 0, 0);
    }
  }
  float sc = args.scale;
  #pragma unroll
  for (int t = 0; t < 2; ++t) {
    int row0 = bi * 64 + qm * 32 + t * 16 + (lane >> 4) * 4;
    #pragma unroll
    for (int u = 0; u < 2; ++u) {
      int col = bj * 64 + qn * 32 + u * 16 + (lane & 15);
      #pragma unroll
      for (int r4 = 0; r4 < 4; ++r4) {
        float v = sc * acc[t][u][r4];
        if (row0 + r4 == col) v += args.diag;
        size_t o = (size_t)(row0 + r4) * CCH + col;
        if (args.outFp32) ((float*)args.D[z])[o] = v;
        else ((u16*)args.D[z])[o] = f2bf(v);
      }
    }
  }
}

// ================= symmetrize + split fp32 -> hi/lo bf16
__global__ __launch_bounds__(256) void symsplit_k(const float* __restrict__ src,
                                                  u16* __restrict__ hi,
                                                  u16* __restrict__ lo) {
  int b = blockIdx.y;
  int ij = blockIdx.x * 256 + threadIdx.x;   // 0..MS-1
  int i = ij >> 9, j = ij & 511;
  size_t base = (size_t)b * MS;
  float v = 0.5f * (src[base + ij] + src[base + (size_t)j * CCH + i]);
  u16 h = f2bf(v);
  hi[base + ij] = h;
  lo[base + ij] = f2bf(v - b2f(h));
}

// ================= split-bf16 matmul (~fp32 quality), 64x64 tiles, Kt=128
struct MMS {
  const u16 *Ah[4], *Al[4], *Bh[4], *Bl[4];
  const u16 *Eh[4], *El[4];
  u16 *Dh[4], *Dl[4];
  float *D32[4];
  u16 *Db[4];
  float scale, beta;
  const float* coefPtr;
};

__global__ __launch_bounds__(256) void mmsplit_k(MMS args) {
  int z = blockIdx.z;
  int bi = blockIdx.y, bj = blockIdx.x;
  __shared__ u16 Ash[64 * 128], Asl[64 * 128], Bsh[64 * 128], Bsl[64 * 128];
  int tid = threadIdx.x, w = tid >> 6, lane = tid & 63;
  int qm = w & 1, qn = w >> 1;
  const u16* sp = (w == 0) ? args.Ah[z] : (w == 1) ? args.Al[z]
                : (w == 2) ? args.Bh[z] : args.Bl[z];
  const u16* ssrc = sp + (size_t)(((w < 2) ? bi : bj) * 64) * CCH;
  u16* sdst = (w == 0) ? Ash : (w == 1) ? Asl : (w == 2) ? Bsh : Bsl;
  f32x4 acc[2][2];
  #pragma unroll
  for (int t = 0; t < 2; ++t)
    #pragma unroll
    for (int u = 0; u < 2; ++u) acc[t][u] = (f32x4)(0.f);

  for (int st = 0; st < 4; ++st) {
    int k0 = st * 128;
    __syncthreads();
    #pragma unroll
    for (int i = 0; i < 16; ++i) stage4(ssrc, CCH, i * 4, k0, sdst, lane);
    __syncthreads();
    #pragma unroll
    for (int s = 0; s < 4; ++s) {
      int cl = s * 4 + (lane >> 4);
      bf16x8 ah[2], al[2], bh[2], bl[2];
      #pragma unroll
      for (int t = 0; t < 2; ++t) {
        int row = qm * 32 + t * 16 + (lane & 15);
        ah[t] = fragld(Ash, row, cl);
        al[t] = fragld(Asl, row, cl);
      }
      #pragma unroll
      for (int u = 0; u < 2; ++u) {
        int row = qn * 32 + u * 16 + (lane & 15);
        bh[u] = fragld(Bsh, row, cl);
        bl[u] = fragld(Bsl, row, cl);
      }
      #pragma unroll
      for (int t = 0; t < 2; ++t)
        #pragma unroll
        for (int u = 0; u < 2; ++u) {
          acc[t][u] = __builtin_amdgcn_mfma_f32_16x16x32_bf16(ah[t], bh[u], acc[t][u], 0, 0, 0);
          acc[t][u] = __builtin_amdgcn_mfma_f32_16x16x32_bf16(ah[t], bl[u], acc[t][u], 0, 0, 0);
          acc[t][u] = __builtin_amdgcn_mfma_f32_16x16x32_bf16(al[t], bh[u], acc[t][u], 0, 0, 0);
        }
    }
  }
  float sc = args.scale;
  if (args.coefPtr) sc *= *args.coefPtr;
  #pragma unroll
  for (int t = 0; t < 2; ++t) {
    int row0 = bi * 64 + qm * 32 + t * 16 + (lane >> 4) * 4;
    #pragma unroll
    for (int u = 0; u < 2; ++u) {
      int col = bj * 64 + qn * 32 + u * 16 + (lane & 15);
      #pragma unroll
      for (int r4 = 0; r4 < 4; ++r4) {
        size_t o = (size_t)(row0 + r4) * CCH + col;
        float v = sc * acc[t][u][r4];
        if (args.beta != 0.f) v += args.beta * (b2f(args.Eh[z][o]) + b2f(args.El[z][o]));
        if (args.D32[z]) args.D32[z][o] = v;
        if (args.Dh[z]) {
          u16 h = f2bf(v);
          args.Dh[z][o] = h;
          args.Dl[z][o] = f2bf(v - b2f(h));
        }
        if (args.Db[z]) args.Db[z][o] = f2bf(v);
      }
    }
  }
}

// ================= mconst[c] = 0.8*ms[c] - (M @ mc)[c]
__global__ __launch_bounds__(256) void mconst_k(const u16* __restrict__ Mb,
                                                const float* __restrict__ mean,
                                                float* __restrict__ mconst) {
  int c = blockIdx.x * 256 + threadIdx.x;   // 0..511
  float s = 0.f;
  for (int j = 0; j < CCH; ++j) s += b2f(Mb[(size_t)c * CCH + j]) * mean[j];
  mconst[c] = 0.8f * mean[CCH + c] - s;
}

// ================= apply: out = fcb @ M^T + mconst + 0.2 X   (128-tiles, Kt=128)
__global__ __launch_bounds__(256) void apply_mfma(const u16* __restrict__ fcb,
                                                  const u16* __restrict__ Mb,
                                                  const float* __restrict__ mconst,
                                                  const float* __restrict__ X,
                                                  float* __restrict__ out) {
  int bi = blockIdx.y;    // n tile (0..127)
  int bj = blockIdx.x;    // c tile (0..3)
  __shared__ u16 As[128 * 128];
  __shared__ u16 Bs[128 * 128];
  int tid = threadIdx.x, w = tid >> 6, lane = tid & 63;
  int qm = w & 1, qn = w >> 1;
  const u16* ssrc = (w < 2) ? fcb + (size_t)(bi * 128) * CCH
                            : Mb + (size_t)(bj * 128) * CCH;
  u16* sdst = (w < 2) ? As : Bs;
  int rbase = (w & 1) * 64;
  f32x4 acc[4][4];
  #pragma unroll
  for (int t = 0; t < 4; ++t)
    #pragma unroll
    for (int u = 0; u < 4; ++u) acc[t][u] = (f32x4)(0.f);

  for (int st = 0; st < 4; ++st) {
    int k0 = st * 128;
    __syncthreads();
    #pragma unroll
    for (int i = 0; i < 16; ++i) stage4(ssrc, CCH, rbase + i * 4, k0, sdst, lane);
    __syncthreads();
    #pragma unroll
    for (int s = 0; s < 4; ++s) {
      int cl = s * 4 + (lane >> 4);
      bf16x8 a[4], bb[4];
      #pragma unroll
      for (int t = 0; t < 4; ++t) a[t] = fragld(As, qm * 64 + t * 16 + (lane & 15), cl);
      #pragma unroll
      for (int u = 0; u < 4; ++u) bb[u] = fragld(Bs, qn * 64 + u * 16 + (lane & 15), cl);
      #pragma unroll
      for (int t = 0; t < 4; ++t)
        #pragma unroll
        for (int u = 0; u < 4; ++u)
          acc[t][u] = __builtin_amdgcn_mfma_f32_16x16x32_bf16(a[t], bb[u], acc[t][u], 0, 0, 0);
    }
  }
  #pragma unroll
  for (int t = 0; t < 4; ++t) {
    int row0 = bi * 128 + qm * 64 + t * 16 + (lane >> 4) * 4;
    #pragma unroll
    for (int u = 0; u < 4; ++u) {
      int col = bj * 128 + qn * 64 + u * 16 + (lane & 15);
      float cst = mconst[col];
      #pragma unroll
      for (int r4 = 0; r4 < 4; ++r4) {
        size_t o = (size_t)(row0 + r4) * CCH + col;
        out[o] = acc[t][u][r4] + cst + 0.2f * X[o];
      }
    }
  }
}

// ================================================================ launcher
extern "C" void kernel_launch(void* const* d_in, const int* in_sizes, int n_in,
                              void* d_out, int out_size, void* d_ws, size_t ws_size,
                              hipStream_t stream) {
  const float* Xc = (const float*)d_in[0];
  const float* Xs = (const float*)d_in[1];
  float* out = (float*)d_out;

  float* f = (float*)d_ws;
  float* sums   = f;                     // 1024
  float* rowsum = f + 1024;              // 1024
  float* G      = f + 2048;              // 2*MS
  float* cov    = G + 2 * MS;            // 2*MS
  float* mean   = cov + 2 * MS;          // 1024
  float* snorm  = mean + 1024;           // 8
  float* coef   = snorm + 8;             // 8
  float* mconst = coef + 8;              // 512
  float* Zf     = mconst + 512;          // 2*MS (fp32, reused for Zr)

  u16* h   = (u16*)(Zf + 2 * MS);
  u16* fct = h;                          // 2*512*16384 u16 (dead after gram)
  u16* fcb = h + (size_t)2 * CCH * NPIX; // 16384*512 u16
  const size_t B2 = 2 * MS;              // u16 elems per 2-batch buffer
  u16* Anh  = fct + 0 * B2;
  u16* Anl  = fct + 1 * B2;
  u16* Y0   = fct + 2 * B2;
  u16* Y1   = fct + 3 * B2;
  u16* Z0   = fct + 4 * B2;
  u16* Z1   = fct + 5 * B2;
  u16* Tb   = fct + 6 * B2;
  u16* Zfsh = fct + 7 * B2;
  u16* Zfsl = fct + 8 * B2;
  u16* Ph   = fct + 9 * B2;
  u16* Pl   = fct + 10 * B2;
  u16* Qh   = fct + 11 * B2;
  u16* Ql   = fct + 12 * B2;
  u16* Zrsh = fct + 13 * B2;
  u16* Zrsl = fct + 14 * B2;
  u16* W2h  = fct + 15 * B2;             // MS each from here
  u16* W2l  = W2h + MS;
  u16* Mb   = W2l + MS;

  hipMemsetAsync(d_ws, 0, (2048 + 2 * MS) * sizeof(float), stream);

  prep_k<<<dim3(256, 8, 2), 256, 0, stream>>>(Xc, Xs, sums, fct, fcb);
  mean_k<<<4, 256, 0, stream>>>(sums, mean);
  gram_mfma<<<dim3(10, 32, 2), 256, 0, stream>>>(fct, G);
  cov_k<<<2048, 256, 0, stream>>>(G, sums, cov, rowsum);
  norm2_k<<<2, 256, 0, stream>>>(rowsum, snorm);
  nsinit_k<<<2048, 256, 0, stream>>>(cov, snorm, Anh, Anl, Y0, Z0);
  coef_k<<<1, 1, 0, stream>>>(snorm, coef);

  // NS with boosted first step (folded into nsinit):  Y1 = Â @ Z1
  {
    MM16 y1{};
    y1.A[0] = Y0;      y1.B[0] = Z0;      y1.D[0] = Y1;
    y1.A[1] = Y0 + MS; y1.B[1] = Z0 + MS; y1.D[1] = Y1 + MS;
    y1.scale = 1.f; y1.diag = 0.f; y1.outFp32 = 0;
    mm16_k<<<dim3(8, 8, 2), 256, 0, stream>>>(y1);
  }
  u16 *Yc = Y1, *Yn = Y0, *Zc = Z0, *Zn = Z1;
  for (int it = 0; it < 4; ++it) {
    MM16 t{};
    t.A[0] = Zc;      t.B[0] = Yc;      t.D[0] = Tb;
    t.A[1] = Zc + MS; t.B[1] = Yc + MS; t.D[1] = Tb + MS;
    t.scale = -1.f; t.diag = 3.f; t.outFp32 = 0;
    mm16_k<<<dim3(8, 8, 2), 256, 0, stream>>>(t);

    if (it < 3) {
      MM16 yz{};
      yz.A[0] = Yc;      yz.B[0] = Tb;      yz.D[0] = Yn;
      yz.A[1] = Yc + MS; yz.B[1] = Tb + MS; yz.D[1] = Yn + MS;
      yz.A[2] = Tb;      yz.B[2] = Zc;      yz.D[2] = Zn;
      yz.A[3] = Tb + MS; yz.B[3] = Zc + MS; yz.D[3] = Zn + MS;
      yz.scale = 0.5f; yz.diag = 0.f; yz.outFp32 = 0;
      mm16_k<<<dim3(8, 8, 4), 256, 0, stream>>>(yz);
      u16* tmp;
      tmp = Yc; Yc = Yn; Yn = tmp;
      tmp = Zc; Zc = Zn; Zn = tmp;
    } else {
      MM16 zf{};
      zf.A[0] = Tb;      zf.B[0] = Zc;      zf.D[0] = Zf;
      zf.A[1] = Tb + MS; zf.B[1] = Zc + MS; zf.D[1] = Zf + MS;
      zf.scale = 0.5f; zf.diag = 0.f; zf.outFp32 = 1;
      mm16_k<<<dim3(8, 8, 2), 256, 0, stream>>>(zf);
    }
  }

  // symmetrize+split Zf
  symsplit_k<<<dim3(1024, 2), 256, 0, stream>>>(Zf, Zfsh, Zfsl);

  // P_b = Zfs_b @ An_b ; Q_b = Zfs_b @ Zfs_b
  MMS pq{};
  for (int b = 0; b < 2; ++b) {
    pq.Ah[b] = Zfsh + b * MS; pq.Al[b] = Zfsl + b * MS;
    pq.Bh[b] = Anh + b * MS;  pq.Bl[b] = Anl + b * MS;
    pq.Dh[b] = Ph + b * MS;   pq.Dl[b] = Pl + b * MS;
    pq.Ah[2 + b] = Zfsh + b * MS; pq.Al[2 + b] = Zfsl + b * MS;
    pq.Bh[2 + b] = Zfsh + b * MS; pq.Bl[2 + b] = Zfsl + b * MS;
    pq.Dh[2 + b] = Qh + b * MS;   pq.Dl[2 + b] = Ql + b * MS;
  }
  pq.scale = 1.f;
  mmsplit_k<<<dim3(8, 8, 4), 256, 0, stream>>>(pq);

  // Zr_b = 1.5 Zfs_b - 0.5 P_b @ Q_b  (fp32 out into Zf)
  MMS zr{};
  for (int b = 0; b < 2; ++b) {
    zr.Ah[b] = Ph + b * MS;   zr.Al[b] = Pl + b * MS;
    zr.Bh[b] = Qh + b * MS;   zr.Bl[b] = Ql + b * MS;
    zr.Eh[b] = Zfsh + b * MS; zr.El[b] = Zfsl + b * MS;
    zr.D32[b] = Zf + b * MS;
  }
  zr.scale = -0.5f; zr.beta = 1.5f;
  mmsplit_k<<<dim3(8, 8, 2), 256, 0, stream>>>(zr);

  // symmetrize+split Zr
  symsplit_k<<<dim3(1024, 2), 256, 0, stream>>>(Zf, Zrsh, Zrsl);

  // W2 = An_s @ Zr_s (split out)
  MMS wv{};
  wv.Ah[0] = Anh + MS;  wv.Al[0] = Anl + MS;
  wv.Bh[0] = Zrsh + MS; wv.Bl[0] = Zrsl + MS;
  wv.Dh[0] = W2h; wv.Dl[0] = W2l;
  wv.scale = 1.f;
  mmsplit_k<<<dim3(8, 8, 1), 256, 0, stream>>>(wv);

  // M = coef * W2 @ Zr_c (bf16 out)
  MMS mv{};
  mv.Ah[0] = W2h;  mv.Al[0] = W2l;
  mv.Bh[0] = Zrsh; mv.Bl[0] = Zrsl;
  mv.Db[0] = Mb;
  mv.scale = 1.f; mv.coefPtr = coef;
  mmsplit_k<<<dim3(8, 8, 1), 256, 0, stream>>>(mv);

  mconst_k<<<2, 256, 0, stream>>>(Mb, mean, mconst);
  apply_mfma<<<dim3(4, 128), 256, 0, stream>>>(fcb, Mb, mconst, Xc, out);
}